// Round 7
// baseline (438.972 us; speedup 1.0000x reference)
//
#include <hip/hip_runtime.h>
#include <math.h>

#define N_NODES 50000
#define N_EDGES 1600000
#define F_IN    256
#define DIMS    64
#define N_CLS   16
#define R_REL   8
#define CAP     96          // per-destination CSR capacity (in-deg ~Poisson(32))

#define PROJ_BLKS 3519      // 391 tiles x 9 "relations" (8 + root slot)
#define CSR_BLKS  3125      // 2 edges/thread: 3125*256*2 == N_EDGES
#define FRONT_BLKS (PROJ_BLKS + CSR_BLKS)   // 6644

typedef short bf16x8 __attribute__((ext_vector_type(8)));
typedef float f32x4  __attribute__((ext_vector_type(4)));
typedef unsigned int u32;
typedef const __attribute__((address_space(1))) u32* gas_ptr;
typedef __attribute__((address_space(3))) u32* las_ptr;

__device__ __forceinline__ void async16(const void* g, void* l) {
    // global->LDS DMA, 16B/lane; LDS dest = uniform base + lane*16
    __builtin_amdgcn_global_load_lds((gas_ptr)g, (las_ptr)l, 16, 0, 0);
}

__device__ __forceinline__ unsigned short f2bf(float f) {
    unsigned u = __float_as_uint(f);
    unsigned r = (u + 0x7fffu + ((u >> 16) & 1u)) >> 16;
    return (unsigned short)r;
}
__device__ __forceinline__ float bf2f(unsigned short u) {
    return __uint_as_float(((unsigned)u) << 16);
}

// ---------- fused convert: x -> bf16 AND wt1[r][n][k] build ----------
__global__ __launch_bounds__(256) void cvt_kernel(
        const float* __restrict__ x, ushort* __restrict__ xb,
        const float* __restrict__ W1, const float* __restrict__ root1,
        ushort* __restrict__ wt1) {
    const int bid = blockIdx.x, t = threadIdx.x;
    if (bid < 12500) {
        int i4 = bid * 256 + t;                    // 3.2M quads
        float4 v = ((const float4*)x)[i4];
        ushort4 o;
        o.x = f2bf(v.x); o.y = f2bf(v.y); o.z = f2bf(v.z); o.w = f2bf(v.w);
        ((ushort4*)xb)[i4] = o;
    } else {
        int idx = (bid - 12500) * 256 + t;         // 9*64*256 = 147456
        int r = idx >> 14, rem = idx & 16383;
        int n = rem >> 8, k = rem & 255;
        float v = (r < 8) ? W1[((size_t)r * F_IN + k) * DIMS + n]
                          : root1[(size_t)k * DIMS + n];
        wt1[idx] = f2bf(v);
    }
}

// ---------- fused front: proj1 MFMA (+si/sj, +x@root1) AND CSR build ----------
// LOCKED round-3 structure: BM=128, 1 relation/block (consecutive blocks
// share one 32KB wt1 slab -> L1-resident B), 3519 proj + 3125 CSR blocks
// interleaved; CSR = 2 edges/thread independent atomic->store chains.
// R1/R2/R5 all proved restructuring proj to cut the 9x staging loses more
// (L1 thrash / wave-count loss) than the fetch saves. Do not touch.
#define BM 128
__global__ __launch_bounds__(256, 6) void front_kernel(
        const ushort* __restrict__ xb, const ushort* __restrict__ wt1,
        const float* __restrict__ at1,
        ushort* __restrict__ xr1b, float* __restrict__ hroot,
        float* __restrict__ si1, float* __restrict__ sj1,
        const int* __restrict__ ei, const int* __restrict__ ecol,
        const float* __restrict__ ew, int* __restrict__ fill,
        unsigned long long* __restrict__ rec) {
    __shared__ ushort xs[BM * 64];                 // 16 KB, swizzled [row][k8^(row&7)]
    const int bid = blockIdx.x;
    const int t = threadIdx.x;

    // interleave: proj/CSR alternate for the first 2*CSR_BLKS bids, then
    // the remaining proj blocks (keeps scatter overlapped with MFMA work)
    int pb = -1, cb = -1;
    if (bid < 2 * CSR_BLKS) { if (bid & 1) cb = bid >> 1; else pb = bid >> 1; }
    else pb = CSR_BLKS + (bid - 2 * CSR_BLKS);

    if (cb >= 0) {
        // ----- CSR build branch: 2 edges/thread, independent chains -----
        int idx = cb * 256 + t;                    // edge-pair index
        int2  s2 = ((const int2*)ei)[idx];
        int2  d2 = ((const int2*)(ei + N_EDGES))[idx];
        int2  c2 = ((const int2*)ecol)[idx];
        float2 w2 = ((const float2*)ew)[idx];
        int p0 = atomicAdd(&fill[d2.x], 1);
        int p1 = atomicAdd(&fill[d2.y], 1);
        unsigned long long r0 =
            ((unsigned long long)__float_as_uint(w2.x) << 32)
            | (unsigned)(s2.x | (c2.x << 16));
        unsigned long long r1 =
            ((unsigned long long)__float_as_uint(w2.y) << 32)
            | (unsigned)(s2.y | (c2.y << 16));
        int i0 = (p0 < CAP) ? d2.x * CAP + p0 : N_NODES * CAP;   // overflow dump
        int i1 = (p1 < CAP) ? d2.y * CAP + p1 : N_NODES * CAP;
        __builtin_nontemporal_store(r0, &rec[i0]);
        __builtin_nontemporal_store(r1, &rec[i1]);
        return;
    }

    // ----- proj1 MFMA branch -----
    const int r = pb / 391;
    const int node0 = (pb % 391) * BM;
    const ushort* wrow = wt1 + (size_t)r * 64 * 256;   // [n][k], L1/L2-resident

    const int w = t >> 6, lane = t & 63;
    const int lane15 = lane & 15, quad = lane >> 4;
    const int row0 = w * 32 + lane15;
    const int sw0 = row0 & 7;

    f32x4 acc[2][4];
    #pragma unroll
    for (int a = 0; a < 2; ++a)
        #pragma unroll
        for (int b = 0; b < 4; ++b)
            acc[a][b] = (f32x4){0.f, 0.f, 0.f, 0.f};

    for (int s = 0; s < 4; ++s) {                  // K staged 4 x 64
        __syncthreads();
        #pragma unroll
        for (int c = 0; c < 4; ++c) {              // 4 x 1024 lane-slots of 16B
            int slot = c * 256 + t;
            int row = slot >> 3, k8p = slot & 7;
            int k8 = k8p ^ (row & 7);              // source-side swizzle
            int node = node0 + row;
            if (node >= N_NODES) node = N_NODES - 1;   // clamp (garbage ok, rows discarded)
            async16(&xb[(size_t)node * 256 + s * 64 + k8 * 8],
                    &xs[(c * 256 + w * 64) * 8]);
        }
        __syncthreads();                           // drains vmcnt incl. lds-DMA
        #pragma unroll
        for (int kk = 0; kk < 2; ++kk) {
            int k8 = kk * 4 + quad;
            int aidx = row0 * 64 + ((k8 ^ sw0) << 3);
            bf16x8 a0 = *(const bf16x8*)&xs[aidx];
            bf16x8 a1 = *(const bf16x8*)&xs[aidx + 16 * 64];
            int kg = s * 64 + kk * 32 + quad * 8;
            #pragma unroll
            for (int nt = 0; nt < 4; ++nt) {
                bf16x8 b = *(const bf16x8*)&wrow[(size_t)(nt * 16 + lane15) * 256 + kg];
                acc[0][nt] = __builtin_amdgcn_mfma_f32_16x16x32_bf16(a0, b, acc[0][nt], 0, 0, 0);
                acc[1][nt] = __builtin_amdgcn_mfma_f32_16x16x32_bf16(a1, b, acc[1][nt], 0, 0, 0);
            }
        }
    }

    const float* at = at1 + r * 128;
    #pragma unroll
    for (int mt = 0; mt < 2; ++mt) {
        float pi[4] = {0.f, 0.f, 0.f, 0.f};
        float pj[4] = {0.f, 0.f, 0.f, 0.f};
        #pragma unroll
        for (int nt = 0; nt < 4; ++nt) {
            int gcol = nt * 16 + lane15;
            float ai = 0.f, aj = 0.f;
            if (r < 8) { ai = at[gcol]; aj = at[64 + gcol]; }
            #pragma unroll
            for (int reg = 0; reg < 4; ++reg) {
                float v = acc[mt][nt][reg];
                int grow = node0 + w * 32 + mt * 16 + quad * 4 + reg;
                if (grow < N_NODES) {
                    if (r < 8)
                        xr1b[((size_t)r * N_NODES + grow) * 64 + gcol] = f2bf(v);
                    else
                        hroot[(size_t)grow * 64 + gcol] = v;
                }
                pi[reg] += ai * v;
                pj[reg] += aj * v;
            }
        }
        if (r < 8) {
            #pragma unroll
            for (int reg = 0; reg < 4; ++reg) {
                float s_ = pi[reg], u_ = pj[reg];
                #pragma unroll
                for (int off = 1; off < 16; off <<= 1) {
                    s_ += __shfl_xor(s_, off, 64);
                    u_ += __shfl_xor(u_, off, 64);
                }
                if (lane15 == 0) {
                    int grow = node0 + w * 32 + mt * 16 + quad * 4 + reg;
                    if (grow < N_NODES) {
                        si1[r * N_NODES + grow] = s_;
                        sj1[r * N_NODES + grow] = u_;
                    }
                }
            }
        }
    }
}

// ---------- layer 1 fused: score + aggregate + relu + proj2 + si2/sj2 + hroot2 ----------
// v8: proj2 folded in as a wave-private epilogue. After the relu'd h row
// lands in LDS (1KB, same-wave produce/consume, no barrier needed), each
// wave computes its own node's h@W2[r] (lane = r*8+cpair, W2 L1-hot),
// emits xr2b/si2/sj2 directly, and precomputes hroot2 = h@root2 so the
// h array never touches global memory and agg2s drops its rsh/hsh phases.
__global__ __launch_bounds__(256) void agg1f_kernel(
        const unsigned long long* __restrict__ rec, const int* __restrict__ fill,
        const float* __restrict__ si, const float* __restrict__ sj,
        const ushort* __restrict__ xr1b, const float* __restrict__ hroot,
        const float* __restrict__ bias1,
        const float* __restrict__ W2, const float* __restrict__ atten2,
        const float* __restrict__ root2,
        ushort* __restrict__ xr2b, float* __restrict__ si2,
        float* __restrict__ sj2, float* __restrict__ hroot2) {
    __shared__ int   esrc[4][CAP];
    __shared__ float ecoef[4][CAP];
    __shared__ float sden[4][8];
    __shared__ int   scnt[4][8];
    __shared__ float ssi[4][8];
    __shared__ float hsh[4][64];
    const int t = threadIdx.x;
    const int w = t >> 6, lane = t & 63;
    const int d = blockIdx.x * 4 + w;              // 12500*4 == N_NODES
    if (lane < 8) {
        sden[w][lane] = 0.f; scnt[w][lane] = 0;
        ssi[w][lane] = si[lane * N_NODES + d];
    }
    const int n = min(fill[d], CAP);
    const int base = d * CAP;
    float ex[2] = {0.f, 0.f}, ww[2] = {0.f, 0.f};
    int cc[2] = {0, 0};
    #pragma unroll
    for (int ii = 0; ii < 2; ++ii) {
        int i = lane + ii * 64;
        if (i < n) {
            unsigned long long rv = rec[base + i];
            int px = (int)(unsigned)rv;
            int s = px & 0xffff, c = (px >> 16) & 0x7fff;
            esrc[w][i] = px;
            float sc = ssi[w][c] + sj[c * N_NODES + s];
            sc = sc > 0.f ? sc : 0.2f * sc;
            float e = __expf(sc);
            ex[ii] = e; cc[ii] = c; ww[ii] = __uint_as_float((unsigned)(rv >> 32));
            atomicAdd(&sden[w][c], e);
            atomicAdd(&scnt[w][c], 1);
        }
    }
    #pragma unroll
    for (int ii = 0; ii < 2; ++ii) {
        int i = lane + ii * 64;
        if (i < n)
            ecoef[w][i] = ex[ii] / fmaxf(sden[w][cc[ii]], 1e-16f)
                          * ww[ii] / (float)scnt[w][cc[ii]];
    }
    // phase 2: half-wave row-pair gather, 16 rows in flight per wave
    const int sub = lane >> 5;                     // 0/1: edge parity
    const int l31 = lane & 31;                     // dim pair: 2*l31, 2*l31+1
    float ax[8] = {0.f,0.f,0.f,0.f,0.f,0.f,0.f,0.f};
    float ay[8] = {0.f,0.f,0.f,0.f,0.f,0.f,0.f,0.f};
    int i0 = 0;
    for (; i0 + 16 <= n; i0 += 16) {
        u32 rv[8]; float cf[8];
        #pragma unroll
        for (int u = 0; u < 8; ++u) {
            int e = i0 + 2 * u + sub;
            int p = esrc[w][e];
            cf[u] = ecoef[w][e];
            int row = (p >> 16) * N_NODES + (p & 0xffff);
            rv[u] = *(const u32*)&xr1b[(size_t)row * 64 + 2 * l31];
        }
        #pragma unroll
        for (int u = 0; u < 8; ++u) {
            ax[u] += cf[u] * bf2f((unsigned short)(rv[u] & 0xffffu));
            ay[u] += cf[u] * bf2f((unsigned short)(rv[u] >> 16));
        }
    }
    for (int e = i0 + sub; e < n; e += 2) {        // tail, 2 rows/instr
        int p = esrc[w][e];
        float c = ecoef[w][e];
        int row = (p >> 16) * N_NODES + (p & 0xffff);
        u32 v = *(const u32*)&xr1b[(size_t)row * 64 + 2 * l31];
        ax[0] += c * bf2f((unsigned short)(v & 0xffffu));
        ay[0] += c * bf2f((unsigned short)(v >> 16));
    }
    float sx = ((ax[0] + ax[1]) + (ax[2] + ax[3])) + ((ax[4] + ax[5]) + (ax[6] + ax[7]));
    float sy = ((ay[0] + ay[1]) + (ay[2] + ay[3])) + ((ay[4] + ay[5]) + (ay[6] + ay[7]));
    sx += __shfl_xor(sx, 32, 64);                  // combine edge parities
    sy += __shfl_xor(sy, 32, 64);
    if (sub == 0) {
        float2 hr = *(const float2*)&hroot[(size_t)d * 64 + 2 * l31];
        float2 bi = *(const float2*)&bias1[2 * l31];
        hsh[w][2 * l31]     = fmaxf(sx + hr.x + bi.x, 0.f);
        hsh[w][2 * l31 + 1] = fmaxf(sy + hr.y + bi.y, 0.f);
    }
    // phase 3 (wave-private, same-wave LDS produce->consume, no barrier):
    // proj2 for this wave's node: lane = r*8 + cpair, c = {2cp, 2cp+1}
    const int r2 = lane >> 3, cp = lane & 7, c0 = cp * 2;
    float acc0 = 0.f, acc1 = 0.f;
    #pragma unroll 8
    for (int k = 0; k < 64; ++k) {
        float hv = hsh[w][k];
        float2 wv = *(const float2*)&W2[((size_t)r2 * 64 + k) * 16 + c0];
        acc0 += hv * wv.x; acc1 += hv * wv.y;
    }
    // si2/sj2 partials, reduce over cpair (lanes differ in low 3 bits)
    float sip = atten2[r2 * 32 + c0]      * acc0 + atten2[r2 * 32 + c0 + 1]  * acc1;
    float sjp = atten2[r2 * 32 + 16 + c0] * acc0 + atten2[r2 * 32 + 17 + c0] * acc1;
    #pragma unroll
    for (int off = 1; off < 8; off <<= 1) {
        sip += __shfl_xor(sip, off, 64);
        sjp += __shfl_xor(sjp, off, 64);
    }
    u32 pk = ((u32)f2bf(acc1) << 16) | (u32)f2bf(acc0);
    *(u32*)&xr2b[((size_t)r2 * N_NODES + d) * 16 + c0] = pk;
    if (cp == 0) {
        si2[r2 * N_NODES + d] = sip;
        sj2[r2 * N_NODES + d] = sjp;
    }
    // phase 4: hroot2 = h @ root2 (lane = kslice*8 + cpair)
    const int ks = lane >> 3;
    float r0a = 0.f, r1a = 0.f;
    #pragma unroll
    for (int kk = 0; kk < 8; ++kk) {
        int k = ks * 8 + kk;
        float hv = hsh[w][k];
        float2 rv = *(const float2*)&root2[(size_t)k * 16 + c0];
        r0a += hv * rv.x; r1a += hv * rv.y;
    }
    #pragma unroll
    for (int off = 8; off < 64; off <<= 1) {
        r0a += __shfl_xor(r0a, off, 64);
        r1a += __shfl_xor(r1a, off, 64);
    }
    if (ks == 0) {
        float2 o2; o2.x = r0a; o2.y = r1a;
        *(float2*)&hroot2[(size_t)d * 16 + c0] = o2;
    }
}

// ---------- layer 2: fused score + aggregate + hroot2 + log_softmax ----------
// v8: rsh/hsh phases removed; root-path comes precomputed via hroot2.
__global__ __launch_bounds__(256) void agg2s_kernel(
        const unsigned long long* __restrict__ rec, const int* __restrict__ fill,
        const float* __restrict__ si, const float* __restrict__ sj,
        const ushort* __restrict__ xr2b, const float* __restrict__ hroot2,
        const float* __restrict__ bias2, float* __restrict__ out) {
    __shared__ int   esrc[4][CAP];
    __shared__ float ecoef[4][CAP];
    __shared__ float sden[4][8];
    __shared__ int   scnt[4][8];
    __shared__ float ssi[4][8];
    const int t = threadIdx.x;
    const int w = t >> 6, lane = t & 63;
    const int d = blockIdx.x * 4 + w;
    if (lane < 8) {
        sden[w][lane] = 0.f; scnt[w][lane] = 0;
        ssi[w][lane] = si[lane * N_NODES + d];
    }
    const int n = min(fill[d], CAP);
    const int base = d * CAP;
    float ex[2] = {0.f, 0.f}, ww[2] = {0.f, 0.f};
    int cc[2] = {0, 0};
    #pragma unroll
    for (int ii = 0; ii < 2; ++ii) {
        int i = lane + ii * 64;
        if (i < n) {
            unsigned long long rv = rec[base + i];
            int px = (int)(unsigned)rv;
            int s = px & 0xffff, c = (px >> 16) & 0x7fff;
            esrc[w][i] = px;
            float sc = ssi[w][c] + sj[c * N_NODES + s];
            sc = sc > 0.f ? sc : 0.2f * sc;
            float e = __expf(sc);
            ex[ii] = e; cc[ii] = c; ww[ii] = __uint_as_float((unsigned)(rv >> 32));
            atomicAdd(&sden[w][c], e);
            atomicAdd(&scnt[w][c], 1);
        }
    }
    #pragma unroll
    for (int ii = 0; ii < 2; ++ii) {
        int i = lane + ii * 64;
        if (i < n)
            ecoef[w][i] = ex[ii] / fmaxf(sden[w][cc[ii]], 1e-16f)
                          * ww[ii] / (float)scnt[w][cc[ii]];
    }
    const int sub = lane >> 4, cd = lane & 15;
    float a0 = 0.f, a1 = 0.f, a2 = 0.f, a3 = 0.f;
    int i = sub;
    for (; i + 12 < n; i += 16) {                  // 4-way unrolled strided gather
        int p0 = esrc[w][i],      p1 = esrc[w][i + 4];
        int p2 = esrc[w][i + 8],  p3 = esrc[w][i + 12];
        float c0 = ecoef[w][i],      c1 = ecoef[w][i + 4];
        float c2 = ecoef[w][i + 8],  c3 = ecoef[w][i + 12];
        int r0 = (p0 >> 16) * N_NODES + (p0 & 0xffff);
        int r1 = (p1 >> 16) * N_NODES + (p1 & 0xffff);
        int r2 = (p2 >> 16) * N_NODES + (p2 & 0xffff);
        int r3 = (p3 >> 16) * N_NODES + (p3 & 0xffff);
        a0 += c0 * bf2f(xr2b[(size_t)r0 * 16 + cd]);
        a1 += c1 * bf2f(xr2b[(size_t)r1 * 16 + cd]);
        a2 += c2 * bf2f(xr2b[(size_t)r2 * 16 + cd]);
        a3 += c3 * bf2f(xr2b[(size_t)r3 * 16 + cd]);
    }
    for (; i < n; i += 4) {
        int p = esrc[w][i];
        int row = (p >> 16) * N_NODES + (p & 0xffff);
        a0 += ecoef[w][i] * bf2f(xr2b[(size_t)row * 16 + cd]);
    }
    float acc = (a0 + a1) + (a2 + a3);
    acc += __shfl_xor(acc, 16, 64);
    acc += __shfl_xor(acc, 32, 64);
    if (sub == 0) {
        acc += hroot2[(size_t)d * 16 + cd] + bias2[cd];
        float m = acc;
        #pragma unroll
        for (int off = 8; off; off >>= 1) m = fmaxf(m, __shfl_xor(m, off, 16));
        float ex2 = expf(acc - m);
        float ssum = ex2;
        #pragma unroll
        for (int off = 8; off; off >>= 1) ssum += __shfl_xor(ssum, off, 16);
        out[(size_t)d * 16 + cd] = acc - m - logf(ssum);
    }
}

extern "C" void kernel_launch(void* const* d_in, const int* in_sizes, int n_in,
                              void* d_out, int out_size, void* d_ws, size_t ws_size,
                              hipStream_t stream) {
    const float* x     = (const float*)d_in[0];
    const int*   ei    = (const int*)  d_in[1];
    const float* ew    = (const float*)d_in[2];
    const int*   ecol  = (const int*)  d_in[3];
    const float* W1    = (const float*)d_in[4];
    const float* at1   = (const float*)d_in[5];
    const float* root1 = (const float*)d_in[6];
    const float* b1    = (const float*)d_in[7];
    const float* W2    = (const float*)d_in[8];
    const float* at2   = (const float*)d_in[9];
    const float* root2 = (const float*)d_in[10];
    const float* b2    = (const float*)d_in[11];
    float* out = (float*)d_out;
    float* ws  = (float*)d_ws;

    // workspace layout (float offsets)
    ushort*   xb     = (ushort*)(ws + 0);          // 12.8M bf16
    ushort*   wt1    = (ushort*)(ws + 6400000);    // 147,456 bf16 [9][64][256]
    ushort*   xr1b   = (ushort*)(ws + 6480000);    // 25.6M bf16 [R,N,64]
    float*    hroot  = ws + 19280000;              // 3.2M
    ushort*   xr2b   = (ushort*)(ws + 22480000);   // 6.4M bf16 [R,N,16]
    float*    si1    = ws + 25680000;              // 400k
    float*    sj1    = ws + 26080000;              // 400k
    float*    si2    = ws + 26480000;              // 400k
    float*    sj2    = ws + 26880000;              // 400k
    int*      fill   = (int*)(ws + 27280000);      // 50k, zeroed
    float*    hroot2 = ws + 27330000;              // 800k [N,16]
    unsigned long long* rec = (unsigned long long*)(ws + 30530000); // 4,800,001 u64

    hipMemsetAsync(fill, 0, (size_t)N_NODES * 4, stream);

    cvt_kernel<<<13076, 256, 0, stream>>>(x, xb, W1, root1, wt1);
    front_kernel<<<FRONT_BLKS, 256, 0, stream>>>(xb, wt1, at1, xr1b, hroot,
                                                 si1, sj1, ei, ecol, ew, fill, rec);
    agg1f_kernel<<<12500, 256, 0, stream>>>(rec, fill, si1, sj1, xr1b, hroot, b1,
                                            W2, at2, root2, xr2b, si2, sj2, hroot2);
    agg2s_kernel<<<12500, 256, 0, stream>>>(rec, fill, si2, sj2, xr2b, hroot2, b2, out);
}

// Round 8
// 384.828 us; speedup vs baseline: 1.1407x; 1.1407x over previous
//
#include <hip/hip_runtime.h>
#include <math.h>

#define N_NODES 50000
#define N_EDGES 1600000
#define F_IN    256
#define DIMS    64
#define N_CLS   16
#define R_REL   8
#define CAP     96          // per-destination CSR capacity (in-deg ~Poisson(32))

#define PROJ_BLKS 3519      // 391 tiles x 9 "relations" (8 + root slot)
#define CSR_BLKS  3125      // 2 edges/thread: 3125*256*2 == N_EDGES
#define FRONT_BLKS (PROJ_BLKS + CSR_BLKS)   // 6644

typedef short bf16x8 __attribute__((ext_vector_type(8)));
typedef float f32x4  __attribute__((ext_vector_type(4)));
typedef unsigned int u32;
typedef const __attribute__((address_space(1))) u32* gas_ptr;
typedef __attribute__((address_space(3))) u32* las_ptr;

__device__ __forceinline__ void async16(const void* g, void* l) {
    // global->LDS DMA, 16B/lane; LDS dest = uniform base + lane*16
    __builtin_amdgcn_global_load_lds((gas_ptr)g, (las_ptr)l, 16, 0, 0);
}

__device__ __forceinline__ unsigned short f2bf(float f) {
    unsigned u = __float_as_uint(f);
    unsigned r = (u + 0x7fffu + ((u >> 16) & 1u)) >> 16;
    return (unsigned short)r;
}
__device__ __forceinline__ float bf2f(unsigned short u) {
    return __uint_as_float(((unsigned)u) << 16);
}

// ---------- fused convert: x -> bf16 AND wt1[r][n][k] build ----------
__global__ __launch_bounds__(256) void cvt_kernel(
        const float* __restrict__ x, ushort* __restrict__ xb,
        const float* __restrict__ W1, const float* __restrict__ root1,
        ushort* __restrict__ wt1) {
    const int bid = blockIdx.x, t = threadIdx.x;
    if (bid < 12500) {
        int i4 = bid * 256 + t;                    // 3.2M quads
        float4 v = ((const float4*)x)[i4];
        ushort4 o;
        o.x = f2bf(v.x); o.y = f2bf(v.y); o.z = f2bf(v.z); o.w = f2bf(v.w);
        ((ushort4*)xb)[i4] = o;
    } else {
        int idx = (bid - 12500) * 256 + t;         // 9*64*256 = 147456
        int r = idx >> 14, rem = idx & 16383;
        int n = rem >> 8, k = rem & 255;
        float v = (r < 8) ? W1[((size_t)r * F_IN + k) * DIMS + n]
                          : root1[(size_t)k * DIMS + n];
        wt1[idx] = f2bf(v);
    }
}

// ---------- fused front: proj1 MFMA (+si/sj, +x@root1) AND CSR build ----------
// LOCKED round-3 structure (verified 146us): BM=128, 1 relation/block,
// 3519 proj + 3125 CSR blocks interleaved; CSR = 2 edges/thread.
// R1/R2/R5 proved restructuring loses more than the fetch saves. Do not touch.
#define BM 128
__global__ __launch_bounds__(256, 6) void front_kernel(
        const ushort* __restrict__ xb, const ushort* __restrict__ wt1,
        const float* __restrict__ at1,
        ushort* __restrict__ xr1b, float* __restrict__ hroot,
        float* __restrict__ si1, float* __restrict__ sj1,
        const int* __restrict__ ei, const int* __restrict__ ecol,
        const float* __restrict__ ew, int* __restrict__ fill,
        unsigned long long* __restrict__ rec) {
    __shared__ ushort xs[BM * 64];                 // 16 KB, swizzled [row][k8^(row&7)]
    const int bid = blockIdx.x;
    const int t = threadIdx.x;

    int pb = -1, cb = -1;
    if (bid < 2 * CSR_BLKS) { if (bid & 1) cb = bid >> 1; else pb = bid >> 1; }
    else pb = CSR_BLKS + (bid - 2 * CSR_BLKS);

    if (cb >= 0) {
        // ----- CSR build branch: 2 edges/thread, independent chains -----
        int idx = cb * 256 + t;                    // edge-pair index
        int2  s2 = ((const int2*)ei)[idx];
        int2  d2 = ((const int2*)(ei + N_EDGES))[idx];
        int2  c2 = ((const int2*)ecol)[idx];
        float2 w2 = ((const float2*)ew)[idx];
        int p0 = atomicAdd(&fill[d2.x], 1);
        int p1 = atomicAdd(&fill[d2.y], 1);
        unsigned long long r0 =
            ((unsigned long long)__float_as_uint(w2.x) << 32)
            | (unsigned)(s2.x | (c2.x << 16));
        unsigned long long r1 =
            ((unsigned long long)__float_as_uint(w2.y) << 32)
            | (unsigned)(s2.y | (c2.y << 16));
        int i0 = (p0 < CAP) ? d2.x * CAP + p0 : N_NODES * CAP;   // overflow dump
        int i1 = (p1 < CAP) ? d2.y * CAP + p1 : N_NODES * CAP;
        __builtin_nontemporal_store(r0, &rec[i0]);
        __builtin_nontemporal_store(r1, &rec[i1]);
        return;
    }

    // ----- proj1 MFMA branch -----
    const int r = pb / 391;
    const int node0 = (pb % 391) * BM;
    const ushort* wrow = wt1 + (size_t)r * 64 * 256;   // [n][k], L1/L2-resident

    const int w = t >> 6, lane = t & 63;
    const int lane15 = lane & 15, quad = lane >> 4;
    const int row0 = w * 32 + lane15;
    const int sw0 = row0 & 7;

    f32x4 acc[2][4];
    #pragma unroll
    for (int a = 0; a < 2; ++a)
        #pragma unroll
        for (int b = 0; b < 4; ++b)
            acc[a][b] = (f32x4){0.f, 0.f, 0.f, 0.f};

    for (int s = 0; s < 4; ++s) {                  // K staged 4 x 64
        __syncthreads();
        #pragma unroll
        for (int c = 0; c < 4; ++c) {              // 4 x 1024 lane-slots of 16B
            int slot = c * 256 + t;
            int row = slot >> 3, k8p = slot & 7;
            int k8 = k8p ^ (row & 7);              // source-side swizzle
            int node = node0 + row;
            if (node >= N_NODES) node = N_NODES - 1;   // clamp (garbage ok, rows discarded)
            async16(&xb[(size_t)node * 256 + s * 64 + k8 * 8],
                    &xs[(c * 256 + w * 64) * 8]);
        }
        __syncthreads();                           // drains vmcnt incl. lds-DMA
        #pragma unroll
        for (int kk = 0; kk < 2; ++kk) {
            int k8 = kk * 4 + quad;
            int aidx = row0 * 64 + ((k8 ^ sw0) << 3);
            bf16x8 a0 = *(const bf16x8*)&xs[aidx];
            bf16x8 a1 = *(const bf16x8*)&xs[aidx + 16 * 64];
            int kg = s * 64 + kk * 32 + quad * 8;
            #pragma unroll
            for (int nt = 0; nt < 4; ++nt) {
                bf16x8 b = *(const bf16x8*)&wrow[(size_t)(nt * 16 + lane15) * 256 + kg];
                acc[0][nt] = __builtin_amdgcn_mfma_f32_16x16x32_bf16(a0, b, acc[0][nt], 0, 0, 0);
                acc[1][nt] = __builtin_amdgcn_mfma_f32_16x16x32_bf16(a1, b, acc[1][nt], 0, 0, 0);
            }
        }
    }

    const float* at = at1 + r * 128;
    #pragma unroll
    for (int mt = 0; mt < 2; ++mt) {
        float pi[4] = {0.f, 0.f, 0.f, 0.f};
        float pj[4] = {0.f, 0.f, 0.f, 0.f};
        #pragma unroll
        for (int nt = 0; nt < 4; ++nt) {
            int gcol = nt * 16 + lane15;
            float ai = 0.f, aj = 0.f;
            if (r < 8) { ai = at[gcol]; aj = at[64 + gcol]; }
            #pragma unroll
            for (int reg = 0; reg < 4; ++reg) {
                float v = acc[mt][nt][reg];
                int grow = node0 + w * 32 + mt * 16 + quad * 4 + reg;
                if (grow < N_NODES) {
                    if (r < 8)
                        xr1b[((size_t)r * N_NODES + grow) * 64 + gcol] = f2bf(v);
                    else
                        hroot[(size_t)grow * 64 + gcol] = v;
                }
                pi[reg] += ai * v;
                pj[reg] += aj * v;
            }
        }
        if (r < 8) {
            #pragma unroll
            for (int reg = 0; reg < 4; ++reg) {
                float s_ = pi[reg], u_ = pj[reg];
                #pragma unroll
                for (int off = 1; off < 16; off <<= 1) {
                    s_ += __shfl_xor(s_, off, 64);
                    u_ += __shfl_xor(u_, off, 64);
                }
                if (lane15 == 0) {
                    int grow = node0 + w * 32 + mt * 16 + quad * 4 + reg;
                    if (grow < N_NODES) {
                        si1[r * N_NODES + grow] = s_;
                        sj1[r * N_NODES + grow] = u_;
                    }
                }
            }
        }
    }
}

// ---------- layer 1: fused score + aggregate + finalize (R6 verbatim) ----------
__global__ __launch_bounds__(256) void agg1s_kernel(
        const unsigned long long* __restrict__ rec, const int* __restrict__ fill,
        const float* __restrict__ si, const float* __restrict__ sj,
        const ushort* __restrict__ xr1b, const float* __restrict__ hroot,
        const float* __restrict__ bias1, float* __restrict__ h) {
    __shared__ int   esrc[4][CAP];
    __shared__ float ecoef[4][CAP];
    __shared__ float sden[4][8];
    __shared__ int   scnt[4][8];
    __shared__ float ssi[4][8];
    const int t = threadIdx.x;
    const int w = t >> 6, lane = t & 63;
    const int d = blockIdx.x * 4 + w;              // 12500*4 == N_NODES
    if (lane < 8) {
        sden[w][lane] = 0.f; scnt[w][lane] = 0;
        ssi[w][lane] = si[lane * N_NODES + d];
    }
    const int n = min(fill[d], CAP);
    const int base = d * CAP;
    float ex[2] = {0.f, 0.f}, ww[2] = {0.f, 0.f};
    int cc[2] = {0, 0};
    #pragma unroll
    for (int ii = 0; ii < 2; ++ii) {
        int i = lane + ii * 64;
        if (i < n) {
            unsigned long long rv = rec[base + i];
            int px = (int)(unsigned)rv;
            int s = px & 0xffff, c = (px >> 16) & 0x7fff;
            esrc[w][i] = px;
            float sc = ssi[w][c] + sj[c * N_NODES + s];
            sc = sc > 0.f ? sc : 0.2f * sc;
            float e = __expf(sc);
            ex[ii] = e; cc[ii] = c; ww[ii] = __uint_as_float((unsigned)(rv >> 32));
            atomicAdd(&sden[w][c], e);
            atomicAdd(&scnt[w][c], 1);
        }
    }
    #pragma unroll
    for (int ii = 0; ii < 2; ++ii) {
        int i = lane + ii * 64;
        if (i < n)
            ecoef[w][i] = ex[ii] / fmaxf(sden[w][cc[ii]], 1e-16f)
                          * ww[ii] / (float)scnt[w][cc[ii]];
    }
    // phase 2: half-wave row-pair gather, 16 rows in flight per wave
    const int sub = lane >> 5;                     // 0/1: edge parity
    const int l31 = lane & 31;                     // dim pair: 2*l31, 2*l31+1
    float ax[8] = {0.f,0.f,0.f,0.f,0.f,0.f,0.f,0.f};
    float ay[8] = {0.f,0.f,0.f,0.f,0.f,0.f,0.f,0.f};
    int i0 = 0;
    for (; i0 + 16 <= n; i0 += 16) {
        u32 rv[8]; float cf[8];
        #pragma unroll
        for (int u = 0; u < 8; ++u) {
            int e = i0 + 2 * u + sub;
            int p = esrc[w][e];
            cf[u] = ecoef[w][e];
            int row = (p >> 16) * N_NODES + (p & 0xffff);
            rv[u] = *(const u32*)&xr1b[(size_t)row * 64 + 2 * l31];
        }
        #pragma unroll
        for (int u = 0; u < 8; ++u) {
            ax[u] += cf[u] * bf2f((unsigned short)(rv[u] & 0xffffu));
            ay[u] += cf[u] * bf2f((unsigned short)(rv[u] >> 16));
        }
    }
    for (int e = i0 + sub; e < n; e += 2) {        // tail, 2 rows/instr
        int p = esrc[w][e];
        float c = ecoef[w][e];
        int row = (p >> 16) * N_NODES + (p & 0xffff);
        u32 v = *(const u32*)&xr1b[(size_t)row * 64 + 2 * l31];
        ax[0] += c * bf2f((unsigned short)(v & 0xffffu));
        ay[0] += c * bf2f((unsigned short)(v >> 16));
    }
    float sx = ((ax[0] + ax[1]) + (ax[2] + ax[3])) + ((ax[4] + ax[5]) + (ax[6] + ax[7]));
    float sy = ((ay[0] + ay[1]) + (ay[2] + ay[3])) + ((ay[4] + ay[5]) + (ay[6] + ay[7]));
    sx += __shfl_xor(sx, 32, 64);                  // combine edge parities
    sy += __shfl_xor(sy, 32, 64);
    if (sub == 0) {
        float2 hr = *(const float2*)&hroot[(size_t)d * 64 + 2 * l31];
        float2 bi = *(const float2*)&bias1[2 * l31];
        float2 o;
        o.x = fmaxf(sx + hr.x + bi.x, 0.f);
        o.y = fmaxf(sy + hr.y + bi.y, 0.f);
        *(float2*)&h[(size_t)d * 64 + 2 * l31] = o;
    }
}

// ---------- layer 2 projection + si2/sj2 + hroot2 (h is LDS-resident here) ----------
__global__ __launch_bounds__(256) void proj2_kernel(
        const float* __restrict__ h, const float* __restrict__ W2,
        const float* __restrict__ atten2, const float* __restrict__ root2,
        ushort* __restrict__ xr2b, float* __restrict__ si2,
        float* __restrict__ sj2, float* __restrict__ hroot2) {
    __shared__ float w2sh[8][64][16];   // 32 KB, [r][k][c]
    __shared__ float a2sh[8][32];
    __shared__ float hsh[32][65];
    const int t = threadIdx.x;
    for (int i = t; i < R_REL * DIMS * N_CLS; i += 256)
        w2sh[i >> 10][(i >> 4) & 63][i & 15] = W2[i];
    if (t < R_REL * 2 * N_CLS) a2sh[t >> 5][t & 31] = atten2[t];
    const int node0 = blockIdx.x * 32;
    for (int i = t; i < 32 * 64; i += 256) {
        int nn = i >> 6, kk = i & 63;
        int node = node0 + nn;
        hsh[nn][kk] = (node < N_NODES) ? h[(size_t)node * 64 + kk] : 0.f;
    }
    __syncthreads();
    const int nl = t & 31, r = t >> 5;
    const int node = node0 + nl;
    float acc[16] = {};
    #pragma unroll 4
    for (int k = 0; k < 64; ++k) {
        float hv = hsh[nl][k];
        #pragma unroll
        for (int c = 0; c < 16; ++c) acc[c] += hv * w2sh[r][k][c];
    }
    if (node < N_NODES) {
        float si = 0.f, sj = 0.f;
        size_t base = ((size_t)r * N_NODES + node) * 16;
        #pragma unroll
        for (int c = 0; c < 16; ++c) {
            si += a2sh[r][c] * acc[c];
            sj += a2sh[r][16 + c] * acc[c];
        }
        #pragma unroll
        for (int c4 = 0; c4 < 4; ++c4) {
            ushort4 o;
            o.x = f2bf(acc[c4 * 4 + 0]); o.y = f2bf(acc[c4 * 4 + 1]);
            o.z = f2bf(acc[c4 * 4 + 2]); o.w = f2bf(acc[c4 * 4 + 3]);
            *(ushort4*)&xr2b[base + c4 * 4] = o;
        }
        si2[r * N_NODES + node] = si;
        sj2[r * N_NODES + node] = sj;
    }
    // hroot2 = h @ root2 for this block's 32 nodes (root2 4KB L1-hot).
    // t -> node nn2 = t>>3, class pair cc0 = (t&7)*2.
    const int nn2 = t >> 3, cc0 = (t & 7) * 2;
    const int node2 = node0 + nn2;
    float h0 = 0.f, h1 = 0.f;
    #pragma unroll 8
    for (int k = 0; k < 64; ++k) {
        float hv = hsh[nn2][k];
        float2 rv = *(const float2*)&root2[(size_t)k * 16 + cc0];
        h0 += hv * rv.x; h1 += hv * rv.y;
    }
    if (node2 < N_NODES) {
        float2 o2; o2.x = h0; o2.y = h1;
        *(float2*)&hroot2[(size_t)node2 * 16 + cc0] = o2;
    }
}

// ---------- layer 2: fused score + aggregate + hroot2 + log_softmax ----------
// v9: u32 gather (lane = sub*8+cl loads 2 classes), 8 subgroups x 2-unroll
// = 16 edges in flight, half the per-edge instructions; rsh/hsh phases and
// the block barrier removed (root path precomputed in proj2 as hroot2).
__global__ __launch_bounds__(256) void agg2s_kernel(
        const unsigned long long* __restrict__ rec, const int* __restrict__ fill,
        const float* __restrict__ si, const float* __restrict__ sj,
        const ushort* __restrict__ xr2b, const float* __restrict__ hroot2,
        const float* __restrict__ bias2, float* __restrict__ out) {
    __shared__ int   esrc[4][CAP];
    __shared__ float ecoef[4][CAP];
    __shared__ float sden[4][8];
    __shared__ int   scnt[4][8];
    __shared__ float ssi[4][8];
    const int t = threadIdx.x;
    const int w = t >> 6, lane = t & 63;
    const int d = blockIdx.x * 4 + w;
    if (lane < 8) {
        sden[w][lane] = 0.f; scnt[w][lane] = 0;
        ssi[w][lane] = si[lane * N_NODES + d];
    }
    const int n = min(fill[d], CAP);
    const int base = d * CAP;
    float ex[2] = {0.f, 0.f}, ww[2] = {0.f, 0.f};
    int cc[2] = {0, 0};
    #pragma unroll
    for (int ii = 0; ii < 2; ++ii) {
        int i = lane + ii * 64;
        if (i < n) {
            unsigned long long rv = rec[base + i];
            int px = (int)(unsigned)rv;
            int s = px & 0xffff, c = (px >> 16) & 0x7fff;
            esrc[w][i] = px;
            float sc = ssi[w][c] + sj[c * N_NODES + s];
            sc = sc > 0.f ? sc : 0.2f * sc;
            float e = __expf(sc);
            ex[ii] = e; cc[ii] = c; ww[ii] = __uint_as_float((unsigned)(rv >> 32));
            atomicAdd(&sden[w][c], e);
            atomicAdd(&scnt[w][c], 1);
        }
    }
    #pragma unroll
    for (int ii = 0; ii < 2; ++ii) {
        int i = lane + ii * 64;
        if (i < n)
            ecoef[w][i] = ex[ii] / fmaxf(sden[w][cc[ii]], 1e-16f)
                          * ww[ii] / (float)scnt[w][cc[ii]];
    }
    // gather: 8 subgroups of 8 lanes; lane holds classes {2cl, 2cl+1}
    const int sub = lane >> 3, cl = lane & 7, c0 = cl * 2;
    float a0x = 0.f, a0y = 0.f, a1x = 0.f, a1y = 0.f;
    int i = sub;
    for (; i + 8 < n; i += 16) {                   // 2-unrolled: edges i, i+8
        int p0 = esrc[w][i], p1 = esrc[w][i + 8];
        float f0 = ecoef[w][i], f1 = ecoef[w][i + 8];
        int r0 = (p0 >> 16) * N_NODES + (p0 & 0xffff);
        int r1 = (p1 >> 16) * N_NODES + (p1 & 0xffff);
        u32 v0 = *(const u32*)&xr2b[(size_t)r0 * 16 + c0];
        u32 v1 = *(const u32*)&xr2b[(size_t)r1 * 16 + c0];
        a0x += f0 * bf2f((unsigned short)(v0 & 0xffffu));
        a0y += f0 * bf2f((unsigned short)(v0 >> 16));
        a1x += f1 * bf2f((unsigned short)(v1 & 0xffffu));
        a1y += f1 * bf2f((unsigned short)(v1 >> 16));
    }
    for (; i < n; i += 8) {                        // tail
        int p = esrc[w][i];
        float f = ecoef[w][i];
        int r0 = (p >> 16) * N_NODES + (p & 0xffff);
        u32 v = *(const u32*)&xr2b[(size_t)r0 * 16 + c0];
        a0x += f * bf2f((unsigned short)(v & 0xffffu));
        a0y += f * bf2f((unsigned short)(v >> 16));
    }
    float accx = a0x + a1x, accy = a0y + a1y;
    accx += __shfl_xor(accx, 8, 64);  accy += __shfl_xor(accy, 8, 64);
    accx += __shfl_xor(accx, 16, 64); accy += __shfl_xor(accy, 16, 64);
    accx += __shfl_xor(accx, 32, 64); accy += __shfl_xor(accy, 32, 64);
    if (sub == 0) {                                // lanes 0..7: classes 2cl,2cl+1
        float2 hr = *(const float2*)&hroot2[(size_t)d * 16 + c0];
        accx += hr.x + bias2[c0];
        accy += hr.y + bias2[c0 + 1];
        float m = fmaxf(accx, accy);
        #pragma unroll
        for (int off = 1; off < 8; off <<= 1) m = fmaxf(m, __shfl_xor(m, off, 64));
        float e0 = expf(accx - m), e1 = expf(accy - m);
        float ssum = e0 + e1;
        #pragma unroll
        for (int off = 1; off < 8; off <<= 1) ssum += __shfl_xor(ssum, off, 64);
        float lse = m + logf(ssum);
        float2 o; o.x = accx - lse; o.y = accy - lse;
        *(float2*)&out[(size_t)d * 16 + c0] = o;
    }
}

extern "C" void kernel_launch(void* const* d_in, const int* in_sizes, int n_in,
                              void* d_out, int out_size, void* d_ws, size_t ws_size,
                              hipStream_t stream) {
    const float* x     = (const float*)d_in[0];
    const int*   ei    = (const int*)  d_in[1];
    const float* ew    = (const float*)d_in[2];
    const int*   ecol  = (const int*)  d_in[3];
    const float* W1    = (const float*)d_in[4];
    const float* at1   = (const float*)d_in[5];
    const float* root1 = (const float*)d_in[6];
    const float* b1    = (const float*)d_in[7];
    const float* W2    = (const float*)d_in[8];
    const float* at2   = (const float*)d_in[9];
    const float* root2 = (const float*)d_in[10];
    const float* b2    = (const float*)d_in[11];
    float* out = (float*)d_out;
    float* ws  = (float*)d_ws;

    // workspace layout (float offsets)
    ushort*   xb     = (ushort*)(ws + 0);          // 12.8M bf16
    ushort*   wt1    = (ushort*)(ws + 6400000);    // 147,456 bf16 [9][64][256]
    ushort*   xr1b   = (ushort*)(ws + 6480000);    // 25.6M bf16 [R,N,64]
    float*    hroot  = ws + 19280000;              // 3.2M (dead after agg1s)
    float*    hroot2 = ws + 19280000;              // 800k, aliases hroot (proj2 runs after agg1s)
    ushort*   xr2b   = (ushort*)(ws + 22480000);   // 6.4M bf16 [R,N,16]
    float*    si1    = ws + 25680000;              // 400k
    float*    sj1    = ws + 26080000;              // 400k
    float*    si2    = ws + 26480000;              // 400k
    float*    sj2    = ws + 26880000;              // 400k
    int*      fill   = (int*)(ws + 27280000);      // 50k, zeroed
    float*    h      = ws + 27330000;              // 3.2M
    unsigned long long* rec = (unsigned long long*)(ws + 30530000); // 4,800,001 u64

    hipMemsetAsync(fill, 0, (size_t)N_NODES * 4, stream);

    cvt_kernel<<<13076, 256, 0, stream>>>(x, xb, W1, root1, wt1);
    front_kernel<<<FRONT_BLKS, 256, 0, stream>>>(xb, wt1, at1, xr1b, hroot,
                                                 si1, sj1, ei, ecol, ew, fill, rec);
    agg1s_kernel<<<12500, 256, 0, stream>>>(rec, fill, si1, sj1, xr1b, hroot, b1, h);
    proj2_kernel<<<1563, 256, 0, stream>>>(h, W2, at2, root2, xr2b, si2, sj2, hroot2);
    agg2s_kernel<<<12500, 256, 0, stream>>>(rec, fill, si2, sj2, xr2b, hroot2, b2, out);
}